// Round 3
// baseline (7150.449 us; speedup 1.0000x reference)
//
#include <hip/hip_runtime.h>
#include <hip/hip_bf16.h>

typedef _Float16 f16;
typedef __attribute__((ext_vector_type(8))) _Float16 f16x8;
typedef __attribute__((ext_vector_type(2))) _Float16 f16x2;
typedef __attribute__((ext_vector_type(4))) float f32x4;

constexpr int CB = 64, CP = 196, CH = 512, CV = 30000, CVP = 30080, CT = 20;

__device__ __forceinline__ float sigf(float x) { return 1.f / (1.f + __expf(-x)); }

// permutation: orig gate row r (q = r>>9 gate type, m = r&511 h-dim) ->
// r' = 32*(m>>3) + 8*q + (m&7); colgroup cg owns cols [32cg,32cg+32) = h-dims [8cg,8cg+8)
__device__ __forceinline__ int pm(int r) {
    return (((r & 511) >> 3) << 5) + ((r >> 9) << 3) + (r & 7);
}

// device-scope barrier; requires all blocks resident (grid=256 = CU count)
__device__ __forceinline__ void gbar(int* cnt, int expected) {
    __threadfence();
    __syncthreads();
    if (threadIdx.x == 0) {
        __hip_atomic_fetch_add(cnt, 1, __ATOMIC_ACQ_REL, __HIP_MEMORY_SCOPE_AGENT);
        while (__hip_atomic_load(cnt, __ATOMIC_ACQUIRE, __HIP_MEMORY_SCOPE_AGENT) < expected) {
            __builtin_amdgcn_s_sleep(2);
        }
    }
    __syncthreads();
    __threadfence();
}

// ---------------------------------------------------------------------------
// mega convert/gather/prep kernel
// ---------------------------------------------------------------------------
__device__ __forceinline__ void cvt8(const float* __restrict__ s, f16* __restrict__ d) {
    float4 a = *(const float4*)s;
    float4 b = *(const float4*)(s + 4);
    f16x8 o;
    o[0] = (f16)a.x; o[1] = (f16)a.y; o[2] = (f16)a.z; o[3] = (f16)a.w;
    o[4] = (f16)b.x; o[5] = (f16)b.y; o[6] = (f16)b.z; o[7] = (f16)b.w;
    *(f16x8*)d = o;
}

__global__ __launch_bounds__(256) void k_mega(
    const float* __restrict__ enc, const float* __restrict__ W_ea,
    const float* __restrict__ W_da, const float* __restrict__ W_fb,
    const float* __restrict__ W_ih, const float* __restrict__ W_hh,
    const float* __restrict__ W_fc, const float* __restrict__ emb,
    const int* __restrict__ caps, const float* __restrict__ b_da,
    const float* __restrict__ b_fb, const float* __restrict__ b_ih,
    const float* __restrict__ b_hh,
    f16* __restrict__ enc_h, f16* __restrict__ Wea_h, f16* __restrict__ Wdafb_h,
    f16* __restrict__ WihE_p, f16* __restrict__ Bg, f16* __restrict__ Wfc_h,
    f16* __restrict__ embg, float* __restrict__ bcat, float* __restrict__ bsum_p,
    int* __restrict__ gsync)
{
    constexpr long long E0 = 802816;    // enc cvt (12544*512/8)
    constexpr long long E1 = 835584;    // W_ea
    constexpr long long E2 = 868352;    // W_da -> Wdafb[0:512]
    constexpr long long E3 = 901120;    // W_fb -> Wdafb[512:1024]
    constexpr long long E4 = 1032192;   // W_ih cols 0..511 perm -> WihE_p
    constexpr long long E5 = 1163264;   // W_ih cols 512..1023 perm -> Bg[:, :512]
    constexpr long long E6 = 1294336;   // W_hh perm -> Bg[:, 512:]
    constexpr long long E7 = 3214336;   // W_fc
    constexpr long long E8 = 3296256;   // emb gather
    constexpr long long E9 = 3301376;   // Wfc pad zeros
    constexpr long long E10 = 3304448;  // biases
    constexpr long long TOT = 3304449;  // + gsync zero

    for (long long id = (long long)blockIdx.x * 256 + threadIdx.x; id < TOT;
         id += (long long)gridDim.x * 256) {
        if (id < E0) {
            cvt8(enc + id * 8, enc_h + id * 8);
        } else if (id < E1) {
            long long c = id - E0; cvt8(W_ea + c * 8, Wea_h + c * 8);
        } else if (id < E2) {
            long long c = id - E1; cvt8(W_da + c * 8, Wdafb_h + c * 8);
        } else if (id < E3) {
            long long c = id - E2; cvt8(W_fb + c * 8, Wdafb_h + 262144 + c * 8);
        } else if (id < E4) {
            long long c = id - E3; int r = (int)(c >> 6), j = (int)(c & 63);
            cvt8(W_ih + (size_t)r * 1024 + j * 8, WihE_p + (size_t)pm(r) * 512 + j * 8);
        } else if (id < E5) {
            long long c = id - E4; int r = (int)(c >> 6), j = (int)(c & 63);
            cvt8(W_ih + (size_t)r * 1024 + 512 + j * 8, Bg + (size_t)pm(r) * 1024 + j * 8);
        } else if (id < E6) {
            long long c = id - E5; int r = (int)(c >> 6), j = (int)(c & 63);
            cvt8(W_hh + (size_t)r * 512 + j * 8, Bg + (size_t)pm(r) * 1024 + 512 + j * 8);
        } else if (id < E7) {
            long long c = id - E6; cvt8(W_fc + c * 8, Wfc_h + c * 8);
        } else if (id < E8) {
            long long c = id - E7; int m = (int)(c >> 6), j = (int)(c & 63);
            int tt = m >> 6, bb = m & 63;
            int row = caps[bb * 21 + tt];
            cvt8(emb + (size_t)row * 512 + j * 8, embg + (size_t)m * 512 + j * 8);
        } else if (id < E9) {
            long long c = id - E8; f16x8 z = {};
            *(f16x8*)&Wfc_h[15360000 + c * 8] = z;
        } else if (id < E10) {
            int i = (int)(id - E9);
            if (i < 512) bcat[i] = b_da[i];
            else if (i < 1024) bcat[i] = b_fb[i - 512];
            else { int r = i - 1024; bsum_p[pm(r)] = b_ih[r] + b_hh[r]; }
        } else {
            *gsync = 0;
        }
    }
}

// h0 = mean_p(enc) -> hbuf slot 0 (f16) and cbuf (f32)
__global__ __launch_bounds__(256) void k_h0(const float* __restrict__ enc,
                                            f16* __restrict__ hbuf, float* __restrict__ cbuf)
{
    int b = blockIdx.x;
    for (int h = threadIdx.x; h < CH; h += 256) {
        const float* p = enc + (size_t)b * CP * CH + h;
        float s = 0.f;
        for (int q = 0; q < CP; ++q) s += p[q * CH];
        s *= (1.f / 196.f);
        hbuf[b * CH + h] = (f16)s;
        cbuf[b * CH + h] = s;
    }
}

// ---------------------------------------------------------------------------
// K=512 GEMM (prologue + preds): tile 128x128, BK=32, padded LDS, reg prefetch
// ---------------------------------------------------------------------------
enum { EPI_F16B = 0, EPI_F32B = 1, EPI_PREDS = 2 };

template <int EPI>
__global__ __launch_bounds__(256) void gemm_k512(
    const f16* __restrict__ Aptr, const f16* __restrict__ Bptr, int N,
    const float* __restrict__ bias, float* __restrict__ Cf,
    f16* __restrict__ Ch, const int* __restrict__ lengths)
{
    constexpr int LD = 40;
    const int tid = threadIdx.x;
    const int lane = tid & 63, wave = tid >> 6;
    const int wr = wave >> 1, wc = wave & 1;
    const int bx = (EPI == EPI_PREDS) ? blockIdx.y : blockIdx.x;
    const int by = (EPI == EPI_PREDS) ? blockIdx.x : blockIdx.y;

    __shared__ f16 As[128 * LD];
    __shared__ f16 Bs[128 * LD];

    const f16* Ag = Aptr + (size_t)by * 128 * 512;
    const f16* Bg = Bptr + (size_t)bx * 128 * 512;

    int srow[2], skc[2];
#pragma unroll
    for (int i = 0; i < 2; ++i) { int ci = tid + i * 256; srow[i] = ci >> 2; skc[i] = (ci & 3) * 8; }

    f32x4 acc[4][4] = {};
    f16x8 ar[2], br[2];
#pragma unroll
    for (int i = 0; i < 2; ++i) {
        ar[i] = *(const f16x8*)&Ag[(size_t)srow[i] * 512 + skc[i]];
        br[i] = *(const f16x8*)&Bg[(size_t)srow[i] * 512 + skc[i]];
    }

    const int rr = lane & 15, kg = (lane >> 4) * 8;
    for (int kt = 0; kt < 16; ++kt) {
        __syncthreads();
#pragma unroll
        for (int i = 0; i < 2; ++i) {
            *(f16x8*)&As[srow[i] * LD + skc[i]] = ar[i];
            *(f16x8*)&Bs[srow[i] * LD + skc[i]] = br[i];
        }
        __syncthreads();
        if (kt < 15) {
            int k0 = (kt + 1) * 32;
#pragma unroll
            for (int i = 0; i < 2; ++i) {
                ar[i] = *(const f16x8*)&Ag[(size_t)srow[i] * 512 + k0 + skc[i]];
                br[i] = *(const f16x8*)&Bg[(size_t)srow[i] * 512 + k0 + skc[i]];
            }
        }
        f16x8 af[4], bf[4];
#pragma unroll
        for (int mi = 0; mi < 4; ++mi) af[mi] = *(const f16x8*)&As[(wr * 64 + mi * 16 + rr) * LD + kg];
#pragma unroll
        for (int ni = 0; ni < 4; ++ni) bf[ni] = *(const f16x8*)&Bs[(wc * 64 + ni * 16 + rr) * LD + kg];
#pragma unroll
        for (int mi = 0; mi < 4; ++mi)
#pragma unroll
            for (int ni = 0; ni < 4; ++ni)
                acc[mi][ni] = __builtin_amdgcn_mfma_f32_16x16x32_f16(af[mi], bf[ni], acc[mi][ni], 0, 0, 0);
    }

    const int m0 = by * 128 + wr * 64;
    const int n0 = bx * 128 + wc * 64;
    const int r0 = (lane >> 4) * 4, cc = lane & 15;
#pragma unroll
    for (int mi = 0; mi < 4; ++mi) {
#pragma unroll
        for (int ni = 0; ni < 4; ++ni) {
#pragma unroll
            for (int r = 0; r < 4; ++r) {
                int m = m0 + mi * 16 + r0 + r;
                int n = n0 + ni * 16 + cc;
                float v = acc[mi][ni][r];
                if constexpr (EPI == EPI_F16B) {
                    Ch[(size_t)m * N + n] = (f16)(v + bias[n]);
                } else if constexpr (EPI == EPI_F32B) {
                    Cf[(size_t)m * N + n] = v + bias[n];
                } else {
                    if (n < CV) {
                        int tt = m >> 6, b = m & 63;
                        float val = ((lengths[b] - 1) > tt) ? (v + bias[n]) : 0.f;
                        __builtin_nontemporal_store(val, &Cf[(size_t)b * (CT * CV) + (size_t)tt * CV + n]);
                    }
                }
            }
        }
    }
}

// ---------------------------------------------------------------------------
// Persistent loop: 256 blocks x 512 threads, 4 device barriers per step.
// A: att2g GEMM (64x1024x512)   [64 colgroups x 4 bgroups, K-split 8 waves]
// B: e[b,p]                     [block (b, p-quarter)]
// C: softmax + awe + xh         [block (b, h-slice)]
// D: gates GEMM (64x2048x1024)+cell [64 colgroups x 4 bgroups]
// ---------------------------------------------------------------------------
__global__ __launch_bounds__(512) void k_loop(
    const f16* __restrict__ att1, const f16* __restrict__ ench,
    const f16* __restrict__ Wdafb, const f16* __restrict__ Bg,
    const float* __restrict__ embIH, const float* __restrict__ Wfa,
    const float* __restrict__ bfa, const float* __restrict__ bcat,
    const int* __restrict__ lens, f16* __restrict__ hbuf,
    float* __restrict__ cbuf, f16* __restrict__ xh,
    float* __restrict__ att2g, float* __restrict__ es_g,
    float* __restrict__ alph, int* __restrict__ gsync)
{
    const int tid = threadIdx.x, lane = tid & 63, wv = tid >> 6;
    const int bid = blockIdx.x;

    __shared__ __align__(16) char smem[115456];

    const float bfa0 = bfa[0];
    int nbar = 0;

    for (int t = 0; t < CT; ++t) {
        // ============ stage A: att2g = h @ Wdafb^T + bcat ============
        {
            const int cg = bid & 63, bg = bid >> 6;
            f16* Ah = (f16*)smem;                       // [16][520]
            f16* Bh = (f16*)(smem + 16640);             // [16][520]
            float* part = (float*)(smem + 33280);       // [8][16][16]
            const f16* hsrc = hbuf + (size_t)t * 32768 + bg * 16 * 512;
            const f16* wsrc = Wdafb + (size_t)cg * 16 * 512;
#pragma unroll
            for (int i = 0; i < 2; ++i) {
                int ci = tid + i * 512;
                int row = ci >> 6, kc = (ci & 63) * 8;
                *(f16x8*)&Ah[row * 520 + kc] = *(const f16x8*)&hsrc[row * 512 + kc];
                *(f16x8*)&Bh[row * 520 + kc] = *(const f16x8*)&wsrc[row * 512 + kc];
            }
            __syncthreads();
            const int rr = lane & 15, kg = (lane >> 4) * 8;
            const int k0 = wv * 64;
            f32x4 acc = {};
#pragma unroll
            for (int ks = 0; ks < 2; ++ks) {
                f16x8 a = *(const f16x8*)&Ah[rr * 520 + k0 + ks * 32 + kg];
                f16x8 b = *(const f16x8*)&Bh[rr * 520 + k0 + ks * 32 + kg];
                acc = __builtin_amdgcn_mfma_f32_16x16x32_f16(a, b, acc, 0, 0, 0);
            }
#pragma unroll
            for (int r = 0; r < 4; ++r)
                part[wv * 256 + ((lane >> 4) * 4 + r) * 16 + rr] = acc[r];
            __syncthreads();
            if (tid < 256) {
                int bl = tid >> 4, cl = tid & 15;
                float s = 0.f;
#pragma unroll
                for (int w = 0; w < 8; ++w) s += part[w * 256 + bl * 16 + cl];
                int col = cg * 16 + cl;
                att2g[(bg * 16 + bl) * 1024 + col] = s + bcat[col];
            }
        }
        gbar(gsync, 256 * (++nbar));

        // ============ stage B: e[b,p] = Wfa . relu(att1 + att2) + bfa ============
        {
            const int b = bid >> 2, q = bid & 3;
            float4 a0 = *(const float4*)&att2g[b * 1024 + lane * 8];
            float4 a1 = *(const float4*)&att2g[b * 1024 + lane * 8 + 4];
            float4 w0 = *(const float4*)&Wfa[lane * 8];
            float4 w1 = *(const float4*)&Wfa[lane * 8 + 4];
            float a2r[8] = {a0.x, a0.y, a0.z, a0.w, a1.x, a1.y, a1.z, a1.w};
            float wfr[8] = {w0.x, w0.y, w0.z, w0.w, w1.x, w1.y, w1.z, w1.w};
            for (int p = q * 49 + wv; p < q * 49 + 49; p += 8) {
                f16x8 av = *(const f16x8*)&att1[((size_t)b * 196 + p) * 512 + lane * 8];
                float s = 0.f;
#pragma unroll
                for (int j = 0; j < 8; ++j)
                    s += fmaxf((float)av[j] + a2r[j], 0.f) * wfr[j];
#pragma unroll
                for (int o = 32; o; o >>= 1) s += __shfl_down(s, o);
                if (lane == 0) es_g[b * 196 + p] = s + bfa0;
            }
        }
        gbar(gsync, 256 * (++nbar));

        // ============ stage C: softmax + awe(h-slice) + xh ============
        {
            const int b = bid >> 2, q = bid & 3;
            float* als = (float*)smem;            // [196]
            float* red = (float*)(smem + 800);    // [16]
            float* awp = (float*)(smem + 896);    // [8][128]
            float ev = (tid < 196) ? es_g[b * 196 + tid] : -1e30f;
            float mx = ev;
#pragma unroll
            for (int o = 32; o; o >>= 1) mx = fmaxf(mx, __shfl_down(mx, o));
            if (lane == 0) red[wv] = mx;
            __syncthreads();
            mx = red[0];
#pragma unroll
            for (int w = 1; w < 8; ++w) mx = fmaxf(mx, red[w]);
            float ex = (tid < 196) ? __expf(ev - mx) : 0.f;
            float sm = ex;
#pragma unroll
            for (int o = 32; o; o >>= 1) sm += __shfl_down(sm, o);
            if (lane == 0) red[8 + wv] = sm;
            __syncthreads();
            sm = red[8];
#pragma unroll
            for (int w = 1; w < 8; ++w) sm += red[8 + w];
            float al = ex / sm;
            if (tid < 196) {
                als[tid] = al;
                if (q == 0)
                    alph[(size_t)b * (CT * 196) + t * 196 + tid] =
                        ((lens[b] - 1) > t) ? al : 0.f;
            }
            __syncthreads();

            const int hbase = q * 128;
            float awx = 0.f, awy = 0.f;
            for (int p = wv; p < 196; p += 8) {
                float a = als[p];
                f16x2 e2 = *(const f16x2*)&ench[((size_t)b * 196 + p) * 512 + hbase + lane * 2];
                awx = fmaf(a, (float)e2[0], awx);
                awy = fmaf(a, (float)e2[1], awy);
            }
            awp[wv * 128 + lane * 2] = awx;
            awp[wv * 128 + lane * 2 + 1] = awy;
            __syncthreads();
            if (tid < 128) {
                float s = 0.f;
#pragma unroll
                for (int w = 0; w < 8; ++w) s += awp[w * 128 + tid];
                float gate = sigf(att2g[b * 1024 + 512 + hbase + tid]);
                xh[b * 1024 + hbase + tid] = (f16)(gate * s);
            } else if (tid < 256) {
                int hh = tid - 128;
                xh[b * 1024 + 512 + hbase + hh] =
                    hbuf[(size_t)t * 32768 + b * 512 + hbase + hh];
            }
        }
        gbar(gsync, 256 * (++nbar));

        // ============ stage D: gates = xh @ Bg^T + embIH -> cell ============
        {
            const int cg = bid & 63, bg = bid >> 6;
            f16* Axs = (f16*)smem;                    // [16][1032]
            f16* Bxs = (f16*)(smem + 33024);          // [32][1032]
            float* part = (float*)(smem + 99072);     // [8][16][32]
            const f16* asrc = xh + bg * 16 * 1024;
            const f16* bsrc = Bg + (size_t)cg * 32 * 1024;
#pragma unroll
            for (int i = 0; i < 4; ++i) {
                int ci = tid + i * 512;
                int row = ci >> 7, kc = (ci & 127) * 8;
                *(f16x8*)&Axs[row * 1032 + kc] = *(const f16x8*)&asrc[row * 1024 + kc];
            }
#pragma unroll
            for (int i = 0; i < 8; ++i) {
                int ci = tid + i * 512;
                int row = ci >> 7, kc = (ci & 127) * 8;
                *(f16x8*)&Bxs[row * 1032 + kc] = *(const f16x8*)&bsrc[row * 1024 + kc];
            }
            __syncthreads();
            const int rr = lane & 15, kg = (lane >> 4) * 8;
            const int k0 = wv * 128;
            f32x4 acc[2] = {};
#pragma unroll
            for (int ks = 0; ks < 4; ++ks) {
                f16x8 a = *(const f16x8*)&Axs[rr * 1032 + k0 + ks * 32 + kg];
#pragma unroll
                for (int nt = 0; nt < 2; ++nt) {
                    f16x8 bb = *(const f16x8*)&Bxs[(nt * 16 + rr) * 1032 + k0 + ks * 32 + kg];
                    acc[nt] = __builtin_amdgcn_mfma_f32_16x16x32_f16(a, bb, acc[nt], 0, 0, 0);
                }
            }
#pragma unroll
            for (int nt = 0; nt < 2; ++nt)
#pragma unroll
                for (int r = 0; r < 4; ++r)
                    part[wv * 512 + ((lane >> 4) * 4 + r) * 32 + nt * 16 + rr] = acc[nt][r];
            __syncthreads();
            if (tid < 128) {
                int bl = tid >> 3, hh = tid & 7;
                float g4[4] = {0.f, 0.f, 0.f, 0.f};
#pragma unroll
                for (int w = 0; w < 8; ++w)
#pragma unroll
                    for (int qg = 0; qg < 4; ++qg)
                        g4[qg] += part[w * 512 + bl * 32 + qg * 8 + hh];
                int b = bg * 16 + bl;
                const float* ei = embIH + (size_t)(t * 64 + b) * 2048 + cg * 32;
                float gi = g4[0] + ei[hh];
                float gf = g4[1] + ei[8 + hh];
                float gg = g4[2] + ei[16 + hh];
                float go = g4[3] + ei[24 + hh];
                int ci = b * 512 + cg * 8 + hh;
                float c = sigf(gf) * cbuf[ci] + sigf(gi) * tanhf(gg);
                cbuf[ci] = c;
                hbuf[(size_t)(t + 1) * 32768 + ci] = (f16)(sigf(go) * tanhf(c));
            }
        }
        gbar(gsync, 256 * (++nbar));
    }
}

// ---------------------------------------------------------------------------
extern "C" void kernel_launch(void* const* d_in, const int* in_sizes, int n_in,
                              void* d_out, int out_size, void* d_ws, size_t ws_size,
                              hipStream_t stream)
{
    const float* enc  = (const float*)d_in[0];
    const int*   caps = (const int*)d_in[1];
    const int*   lens = (const int*)d_in[2];
    const float* emb  = (const float*)d_in[3];
    const float* W_ea = (const float*)d_in[4];
    const float* b_ea = (const float*)d_in[5];
    const float* W_da = (const float*)d_in[6];
    const float* b_da = (const float*)d_in[7];
    const float* W_fa = (const float*)d_in[8];
    const float* b_fa = (const float*)d_in[9];
    const float* W_fb = (const float*)d_in[10];
    const float* b_fb = (const float*)d_in[11];
    const float* W_ih = (const float*)d_in[12];
    const float* W_hh = (const float*)d_in[13];
    const float* b_ih = (const float*)d_in[14];
    const float* b_hh = (const float*)d_in[15];
    const float* W_fc = (const float*)d_in[16];
    const float* b_fc = (const float*)d_in[17];

    float* out = (float*)d_out;
    float* alph_out = out + (size_t)CB * CT * CV;

    char* p = (char*)d_ws;
    auto carve = [&](size_t bytes) {
        char* r = p;
        p += (bytes + 255) & ~(size_t)255;
        return r;
    };
    f16* enc_h   = (f16*)carve((size_t)12544 * 512 * 2);
    f16* att1_h  = (f16*)carve((size_t)12544 * 512 * 2);
    f16* Wea_h   = (f16*)carve((size_t)512 * 512 * 2);
    f16* Wdafb_h = (f16*)carve((size_t)1024 * 512 * 2);
    f16* WihE_p  = (f16*)carve((size_t)2048 * 512 * 2);
    f16* Bg_h    = (f16*)carve((size_t)2048 * 1024 * 2);
    f16* Wfc_h   = (f16*)carve((size_t)CVP * 512 * 2);
    f16* embg    = (f16*)carve((size_t)1280 * 512 * 2);
    float* embIH = (float*)carve((size_t)1280 * 2048 * 4);
    float* bcat  = (float*)carve(1024 * 4);
    float* bsum_p= (float*)carve(2048 * 4);
    f16* hbuf    = (f16*)carve((size_t)21 * 64 * 512 * 2);
    float* cbuf  = (float*)carve((size_t)64 * 512 * 4);
    f16* xh      = (f16*)carve((size_t)64 * 1024 * 2);
    float* att2g = (float*)carve((size_t)64 * 1024 * 4);
    float* es_g  = (float*)carve((size_t)64 * 196 * 4);
    int* gsync   = (int*)carve(256);

    hipLaunchKernelGGL(k_mega, dim3(4096), dim3(256), 0, stream,
                       enc, W_ea, W_da, W_fb, W_ih, W_hh, W_fc, emb, caps,
                       b_da, b_fb, b_ih, b_hh,
                       enc_h, Wea_h, Wdafb_h, WihE_p, Bg_h, Wfc_h, embg, bcat, bsum_p, gsync);

    hipLaunchKernelGGL(k_h0, dim3(64), dim3(256), 0, stream, enc, hbuf, cbuf);

    // att1 = enc_h @ W_ea^T + b_ea  (M=12544, N=512) -> f16
    hipLaunchKernelGGL((gemm_k512<EPI_F16B>), dim3(4, 98), dim3(256), 0, stream,
                       enc_h, Wea_h, 512, b_ea, (float*)nullptr, att1_h, (const int*)nullptr);
    // embIH = embg @ WihE_p^T + bsum_p  (M=1280, N=2048 permuted) -> f32
    hipLaunchKernelGGL((gemm_k512<EPI_F32B>), dim3(16, 10), dim3(256), 0, stream,
                       embg, WihE_p, 2048, bsum_p, embIH, (f16*)nullptr, (const int*)nullptr);

    // persistent 20-step loop: 256 blocks x 512 threads
    hipLaunchKernelGGL(k_loop, dim3(256), dim3(512), 0, stream,
                       att1_h, enc_h, Wdafb_h, Bg_h, embIH, W_fa, b_fa, bcat,
                       lens, hbuf, cbuf, xh, att2g, es_g, alph_out, gsync);

    // predictions = h(1..20) @ W_fc^T + b_fc, masked scatter
    hipLaunchKernelGGL((gemm_k512<EPI_PREDS>), dim3(10, CVP / 128), dim3(256), 0, stream,
                       hbuf + 32768, Wfc_h, CVP, b_fc, out, (f16*)nullptr, lens);
}

// Round 4
// 904.440 us; speedup vs baseline: 7.9059x; 7.9059x over previous
//
#include <hip/hip_runtime.h>
#include <hip/hip_bf16.h>

typedef _Float16 f16;
typedef __attribute__((ext_vector_type(8))) _Float16 f16x8;
typedef __attribute__((ext_vector_type(4))) float f32x4;

constexpr int CB = 64, CP = 196, CH = 512, CV = 30000, CVP = 30080, CT = 20;

__device__ __forceinline__ float sigf(float x) { return 1.f / (1.f + __expf(-x)); }

// permutation: orig gate row r (q = r>>9 gate type, m = r&511 h-dim) ->
// r' = 32*(m>>3) + 8*q + (m&7); colgroup cg owns cols [32cg,32cg+32) = h-dims [8cg,8cg+8)
__device__ __forceinline__ int pm(int r) {
    return (((r & 511) >> 3) << 5) + ((r >> 9) << 3) + (r & 7);
}

// ---- relaxed agent-scope (sc1, L3-coherent) access helpers: no L2 dirt, no staleness
__device__ __forceinline__ unsigned ald_u(const unsigned* p) {
    return __hip_atomic_load(p, __ATOMIC_RELAXED, __HIP_MEMORY_SCOPE_AGENT);
}
__device__ __forceinline__ void ast_u(unsigned* p, unsigned v) {
    __hip_atomic_store(p, v, __ATOMIC_RELAXED, __HIP_MEMORY_SCOPE_AGENT);
}
__device__ __forceinline__ float ald_f(const float* p) {
    return __hip_atomic_load(p, __ATOMIC_RELAXED, __HIP_MEMORY_SCOPE_AGENT);
}
__device__ __forceinline__ void ast_f(float* p, float v) {
    __hip_atomic_store(p, v, __ATOMIC_RELAXED, __HIP_MEMORY_SCOPE_AGENT);
}
__device__ __forceinline__ f16x8 ald_h8(const f16* p) {
    const unsigned* u = (const unsigned*)p;
    union { unsigned w[4]; f16x8 h; } r;
    r.w[0] = ald_u(u); r.w[1] = ald_u(u + 1);
    r.w[2] = ald_u(u + 2); r.w[3] = ald_u(u + 3);
    return r.h;
}

// device barrier, fence-free: all data goes through sc1 (L3) so no wbl2/inv needed.
// 2-level counter tree: 32 groups of 8 blocks -> root. Monotonic, never reset.
__device__ __forceinline__ void gbar(int* gs, int nbar) {
    __syncthreads();  // compiler drains vmcnt(0) per wave before s_barrier
    if (threadIdx.x == 0) {
        int* gc = gs + 16 * ((blockIdx.x >> 3) + 1);
        int old = __hip_atomic_fetch_add(gc, 1, __ATOMIC_RELAXED, __HIP_MEMORY_SCOPE_AGENT);
        if (old == 8 * nbar - 1)
            __hip_atomic_fetch_add(gs, 1, __ATOMIC_RELAXED, __HIP_MEMORY_SCOPE_AGENT);
        while (__hip_atomic_load(gs, __ATOMIC_RELAXED, __HIP_MEMORY_SCOPE_AGENT) < 32 * nbar)
            __builtin_amdgcn_s_sleep(1);
    }
    __syncthreads();
}

// ---------------------------------------------------------------------------
// mega convert/gather/prep kernel
// ---------------------------------------------------------------------------
__device__ __forceinline__ void cvt8(const float* __restrict__ s, f16* __restrict__ d) {
    float4 a = *(const float4*)s;
    float4 b = *(const float4*)(s + 4);
    f16x8 o;
    o[0] = (f16)a.x; o[1] = (f16)a.y; o[2] = (f16)a.z; o[3] = (f16)a.w;
    o[4] = (f16)b.x; o[5] = (f16)b.y; o[6] = (f16)b.z; o[7] = (f16)b.w;
    *(f16x8*)d = o;
}

__global__ __launch_bounds__(256) void k_mega(
    const float* __restrict__ enc, const float* __restrict__ W_ea,
    const float* __restrict__ W_da, const float* __restrict__ W_fb,
    const float* __restrict__ W_ih, const float* __restrict__ W_hh,
    const float* __restrict__ W_fc, const float* __restrict__ emb,
    const int* __restrict__ caps, const float* __restrict__ b_da,
    const float* __restrict__ b_fb, const float* __restrict__ b_ih,
    const float* __restrict__ b_hh,
    f16* __restrict__ enc_h, f16* __restrict__ Wea_h, f16* __restrict__ Wdafb_h,
    f16* __restrict__ WihE_p, f16* __restrict__ Bg, f16* __restrict__ Wfc_h,
    f16* __restrict__ embg, float* __restrict__ bcat, float* __restrict__ bsum_p,
    int* __restrict__ gsync)
{
    constexpr long long E0 = 802816;    // enc cvt (12544*512/8)
    constexpr long long E1 = 835584;    // W_ea
    constexpr long long E2 = 868352;    // W_da -> Wdafb[0:512]
    constexpr long long E3 = 901120;    // W_fb -> Wdafb[512:1024]
    constexpr long long E4 = 1032192;   // W_ih cols 0..511 perm -> WihE_p
    constexpr long long E5 = 1163264;   // W_ih cols 512..1023 perm -> Bg[:, :512]
    constexpr long long E6 = 1294336;   // W_hh perm -> Bg[:, 512:]
    constexpr long long E7 = 3214336;   // W_fc
    constexpr long long E8 = 3296256;   // emb gather
    constexpr long long E9 = 3301376;   // Wfc pad zeros
    constexpr long long E10 = 3304448;  // biases
    constexpr long long TOT = 3305472;  // + gsync zero (1024 ints)

    for (long long id = (long long)blockIdx.x * 256 + threadIdx.x; id < TOT;
         id += (long long)gridDim.x * 256) {
        if (id < E0) {
            cvt8(enc + id * 8, enc_h + id * 8);
        } else if (id < E1) {
            long long c = id - E0; cvt8(W_ea + c * 8, Wea_h + c * 8);
        } else if (id < E2) {
            long long c = id - E1; cvt8(W_da + c * 8, Wdafb_h + c * 8);
        } else if (id < E3) {
            long long c = id - E2; cvt8(W_fb + c * 8, Wdafb_h + 262144 + c * 8);
        } else if (id < E4) {
            long long c = id - E3; int r = (int)(c >> 6), j = (int)(c & 63);
            cvt8(W_ih + (size_t)r * 1024 + j * 8, WihE_p + (size_t)pm(r) * 512 + j * 8);
        } else if (id < E5) {
            long long c = id - E4; int r = (int)(c >> 6), j = (int)(c & 63);
            cvt8(W_ih + (size_t)r * 1024 + 512 + j * 8, Bg + (size_t)pm(r) * 1024 + j * 8);
        } else if (id < E6) {
            long long c = id - E5; int r = (int)(c >> 6), j = (int)(c & 63);
            cvt8(W_hh + (size_t)r * 512 + j * 8, Bg + (size_t)pm(r) * 1024 + 512 + j * 8);
        } else if (id < E7) {
            long long c = id - E6; cvt8(W_fc + c * 8, Wfc_h + c * 8);
        } else if (id < E8) {
            long long c = id - E7; int m = (int)(c >> 6), j = (int)(c & 63);
            int tt = m >> 6, bb = m & 63;
            int row = caps[bb * 21 + tt];
            cvt8(emb + (size_t)row * 512 + j * 8, embg + (size_t)m * 512 + j * 8);
        } else if (id < E9) {
            long long c = id - E8; f16x8 z = {};
            *(f16x8*)&Wfc_h[15360000 + c * 8] = z;
        } else if (id < E10) {
            int i = (int)(id - E9);
            if (i < 512) bcat[i] = b_da[i];
            else if (i < 1024) bcat[i] = b_fb[i - 512];
            else { int r = i - 1024; bsum_p[pm(r)] = b_ih[r] + b_hh[r]; }
        } else {
            gsync[(int)(id - E10)] = 0;
        }
    }
}

// h0 = mean_p(enc) -> hbuf slot 0 (f16) and cbuf (f32)
__global__ __launch_bounds__(256) void k_h0(const float* __restrict__ enc,
                                            f16* __restrict__ hbuf, float* __restrict__ cbuf)
{
    int b = blockIdx.x;
    for (int h = threadIdx.x; h < CH; h += 256) {
        const float* p = enc + (size_t)b * CP * CH + h;
        float s = 0.f;
        for (int q = 0; q < CP; ++q) s += p[q * CH];
        s *= (1.f / 196.f);
        hbuf[b * CH + h] = (f16)s;
        cbuf[b * CH + h] = s;
    }
}

// ---------------------------------------------------------------------------
// K=512 GEMM (prologue + preds): tile 128x128, BK=32, padded LDS, reg prefetch
// ---------------------------------------------------------------------------
enum { EPI_F16B = 0, EPI_F32B = 1, EPI_PREDS = 2 };

template <int EPI>
__global__ __launch_bounds__(256) void gemm_k512(
    const f16* __restrict__ Aptr, const f16* __restrict__ Bptr, int N,
    const float* __restrict__ bias, float* __restrict__ Cf,
    f16* __restrict__ Ch, const int* __restrict__ lengths)
{
    constexpr int LD = 40;
    const int tid = threadIdx.x;
    const int lane = tid & 63, wave = tid >> 6;
    const int wr = wave >> 1, wc = wave & 1;
    const int bx = (EPI == EPI_PREDS) ? blockIdx.y : blockIdx.x;
    const int by = (EPI == EPI_PREDS) ? blockIdx.x : blockIdx.y;

    __shared__ f16 As[128 * LD];
    __shared__ f16 Bs[128 * LD];

    const f16* Ag = Aptr + (size_t)by * 128 * 512;
    const f16* Bg = Bptr + (size_t)bx * 128 * 512;

    int srow[2], skc[2];
#pragma unroll
    for (int i = 0; i < 2; ++i) { int ci = tid + i * 256; srow[i] = ci >> 2; skc[i] = (ci & 3) * 8; }

    f32x4 acc[4][4] = {};
    f16x8 ar[2], br[2];
#pragma unroll
    for (int i = 0; i < 2; ++i) {
        ar[i] = *(const f16x8*)&Ag[(size_t)srow[i] * 512 + skc[i]];
        br[i] = *(const f16x8*)&Bg[(size_t)srow[i] * 512 + skc[i]];
    }

    const int rr = lane & 15, kg = (lane >> 4) * 8;
    for (int kt = 0; kt < 16; ++kt) {
        __syncthreads();
#pragma unroll
        for (int i = 0; i < 2; ++i) {
            *(f16x8*)&As[srow[i] * LD + skc[i]] = ar[i];
            *(f16x8*)&Bs[srow[i] * LD + skc[i]] = br[i];
        }
        __syncthreads();
        if (kt < 15) {
            int k0 = (kt + 1) * 32;
#pragma unroll
            for (int i = 0; i < 2; ++i) {
                ar[i] = *(const f16x8*)&Ag[(size_t)srow[i] * 512 + k0 + skc[i]];
                br[i] = *(const f16x8*)&Bg[(size_t)srow[i] * 512 + k0 + skc[i]];
            }
        }
        f16x8 af[4], bf[4];
#pragma unroll
        for (int mi = 0; mi < 4; ++mi) af[mi] = *(const f16x8*)&As[(wr * 64 + mi * 16 + rr) * LD + kg];
#pragma unroll
        for (int ni = 0; ni < 4; ++ni) bf[ni] = *(const f16x8*)&Bs[(wc * 64 + ni * 16 + rr) * LD + kg];
#pragma unroll
        for (int mi = 0; mi < 4; ++mi)
#pragma unroll
            for (int ni = 0; ni < 4; ++ni)
                acc[mi][ni] = __builtin_amdgcn_mfma_f32_16x16x32_f16(af[mi], bf[ni], acc[mi][ni], 0, 0, 0);
    }

    const int m0 = by * 128 + wr * 64;
    const int n0 = bx * 128 + wc * 64;
    const int r0 = (lane >> 4) * 4, cc = lane & 15;
#pragma unroll
    for (int mi = 0; mi < 4; ++mi) {
#pragma unroll
        for (int ni = 0; ni < 4; ++ni) {
#pragma unroll
            for (int r = 0; r < 4; ++r) {
                int m = m0 + mi * 16 + r0 + r;
                int n = n0 + ni * 16 + cc;
                float v = acc[mi][ni][r];
                if constexpr (EPI == EPI_F16B) {
                    Ch[(size_t)m * N + n] = (f16)(v + bias[n]);
                } else if constexpr (EPI == EPI_F32B) {
                    Cf[(size_t)m * N + n] = v + bias[n];
                } else {
                    if (n < CV) {
                        int tt = m >> 6, b = m & 63;
                        float val = ((lengths[b] - 1) > tt) ? (v + bias[n]) : 0.f;
                        __builtin_nontemporal_store(val, &Cf[(size_t)b * (CT * CV) + (size_t)tt * CV + n]);
                    }
                }
            }
        }
    }
}

// ---------------------------------------------------------------------------
// Persistent loop: 256 blocks x 512 threads, 3 fence-free barriers per step.
// A : att2g[64,1024] = h @ Wdafb^T + bcat      (64 cg x 4 bg, K-split 8 waves)
// BC: e -> softmax -> awe -> xh                 (blocks 0..63, one per batch)
// D : gates[64,2048] = [xh;h] @ Bg^T + embIH -> LSTM cell -> h_{t+1}
// Frag loads straight from global (no reuse within block); LDS only for the
// 8-wave f32 partial reduce. cg grouped by XCD (bid&7) for L2 locality.
// ---------------------------------------------------------------------------
__global__ __launch_bounds__(512) void k_loop(
    const f16* __restrict__ att1, const f16* __restrict__ ench,
    const f16* __restrict__ Wdafb, const f16* __restrict__ Bg,
    const float* __restrict__ embIH, const float* __restrict__ Wfa,
    const float* __restrict__ bfa, const float* __restrict__ bcat,
    const int* __restrict__ lens, f16* __restrict__ hbuf,
    float* __restrict__ cbuf, f16* __restrict__ xh,
    float* __restrict__ att2g, float* __restrict__ alph, int* __restrict__ gsync)
{
    const int tid = threadIdx.x, lane = tid & 63, wv = tid >> 6;
    const int bid = blockIdx.x;
    const int cg = (bid & 7) * 8 + ((bid >> 3) & 7);  // column-group, XCD-pinned
    const int bg = bid >> 6;                          // batch-group 0..3

    __shared__ __align__(16) char smem[22144];

    const int rr = lane & 15, kg = (lane >> 4) * 8;
    const int r0 = (lane >> 4) * 4, cc = lane & 15;
    const float bfa0 = bfa[0];
    int nbar = 0;

    for (int t = 0; t < CT; ++t) {
        const f16* hsrc = hbuf + (size_t)t * 32768;

        // ================= stage A: att2g = h @ Wdafb^T + bcat =================
        {
            float* part = (float*)smem;  // [8][256]
            f32x4 acc = {};
            const int kb = wv * 64;
#pragma unroll
            for (int ks = 0; ks < 2; ++ks) {
                int k = kb + ks * 32 + kg;
                f16x8 a = ald_h8(&hsrc[(bg * 16 + rr) * 512 + k]);
                f16x8 b = *(const f16x8*)&Wdafb[(size_t)(cg * 16 + rr) * 512 + k];
                acc = __builtin_amdgcn_mfma_f32_16x16x32_f16(a, b, acc, 0, 0, 0);
            }
#pragma unroll
            for (int r = 0; r < 4; ++r)
                part[wv * 256 + (r0 + r) * 16 + cc] = acc[r];
            __syncthreads();
            if (tid < 256) {
                float s = 0.f;
#pragma unroll
                for (int w = 0; w < 8; ++w) s += part[w * 256 + tid];
                int m = tid >> 4, n = tid & 15;
                ast_f(&att2g[(bg * 16 + m) * 1024 + cg * 16 + n], s + bcat[cg * 16 + n]);
            }
        }
        gbar(gsync, ++nbar);

        // ========== stage BC: e, softmax, awe, xh (blocks 0..63) ==========
        if (bid < 64) {
            const int b = bid;
            float* att2s = (float*)smem;           // [1024] f32
            float* es    = (float*)(smem + 4096);  // [196]
            float* als   = (float*)(smem + 4880);  // [196]
            float* red   = (float*)(smem + 5664);  // [16]
            float* awp   = (float*)(smem + 5760);  // [8][512]
            att2s[tid * 2]     = ald_f(&att2g[b * 1024 + tid * 2]);
            att2s[tid * 2 + 1] = ald_f(&att2g[b * 1024 + tid * 2 + 1]);
            __syncthreads();

            float a2r[8], wfr[8];
#pragma unroll
            for (int j = 0; j < 8; ++j) {
                a2r[j] = att2s[lane * 8 + j];
                wfr[j] = Wfa[lane * 8 + j];
            }
            for (int p = wv; p < CP; p += 8) {
                f16x8 av = *(const f16x8*)&att1[((size_t)b * CP + p) * 512 + lane * 8];
                float s = 0.f;
#pragma unroll
                for (int j = 0; j < 8; ++j)
                    s += fmaxf((float)av[j] + a2r[j], 0.f) * wfr[j];
#pragma unroll
                for (int o = 32; o; o >>= 1) s += __shfl_down(s, o);
                if (lane == 0) es[p] = s + bfa0;
            }
            __syncthreads();

            float ev = (tid < CP) ? es[tid] : -1e30f;
            float mx = ev;
#pragma unroll
            for (int o = 32; o; o >>= 1) mx = fmaxf(mx, __shfl_down(mx, o));
            if (lane == 0) red[wv] = mx;
            __syncthreads();
            mx = red[0];
#pragma unroll
            for (int w = 1; w < 8; ++w) mx = fmaxf(mx, red[w]);
            float ex = (tid < CP) ? __expf(ev - mx) : 0.f;
            float sm = ex;
#pragma unroll
            for (int o = 32; o; o >>= 1) sm += __shfl_down(sm, o);
            if (lane == 0) red[8 + wv] = sm;
            __syncthreads();
            sm = red[8];
#pragma unroll
            for (int w = 1; w < 8; ++w) sm += red[8 + w];
            float al = ex / sm;
            if (tid < CP) {
                als[tid] = al;
                alph[(size_t)b * (CT * CP) + t * CP + tid] = ((lens[b] - 1) > t) ? al : 0.f;
            }
            __syncthreads();

            float aw[8] = {};
            for (int p = wv; p < CP; p += 8) {
                float a = als[p];
                f16x8 e8 = *(const f16x8*)&ench[((size_t)b * CP + p) * 512 + lane * 8];
#pragma unroll
                for (int j = 0; j < 8; ++j) aw[j] = fmaf(a, (float)e8[j], aw[j]);
            }
#pragma unroll
            for (int j = 0; j < 8; ++j) awp[wv * 512 + lane * 8 + j] = aw[j];
            __syncthreads();
            if (tid < 256) {
                int h2 = tid * 2;
                float s0 = 0.f, s1 = 0.f;
#pragma unroll
                for (int w = 0; w < 8; ++w) {
                    s0 += awp[w * 512 + h2];
                    s1 += awp[w * 512 + h2 + 1];
                }
                union { f16 h[2]; unsigned u; } pk;
                pk.h[0] = (f16)(sigf(att2s[512 + h2]) * s0);
                pk.h[1] = (f16)(sigf(att2s[512 + h2 + 1]) * s1);
                ast_u((unsigned*)xh + b * 256 + tid, pk.u);
            }
        }
        gbar(gsync, ++nbar);

        // ===== stage D: gates = [xh;h] @ Bg^T + embIH -> cell -> h_{t+1} =====
        {
            float* part = (float*)smem;            // [8][512]
            float* gsum = (float*)(smem + 16384);  // [512]
            f32x4 acc[2] = {};
            const int kb = wv * 128;
            const int row = bg * 16 + rr;
#pragma unroll
            for (int ks = 0; ks < 4; ++ks) {
                int k = kb + ks * 32 + kg;
                f16x8 a = (k < 512) ? ald_h8(&xh[row * 512 + k])
                                    : ald_h8(&hsrc[row * 512 + (k - 512)]);
#pragma unroll
                for (int nt = 0; nt < 2; ++nt) {
                    f16x8 b = *(const f16x8*)&Bg[(size_t)(cg * 32 + nt * 16 + rr) * 1024 + k];
                    acc[nt] = __builtin_amdgcn_mfma_f32_16x16x32_f16(a, b, acc[nt], 0, 0, 0);
                }
            }
#pragma unroll
            for (int nt = 0; nt < 2; ++nt)
#pragma unroll
                for (int r = 0; r < 4; ++r)
                    part[wv * 512 + (r0 + r) * 32 + nt * 16 + cc] = acc[nt][r];
            __syncthreads();
            {
                float s = 0.f;
#pragma unroll
                for (int w = 0; w < 8; ++w) s += part[w * 512 + tid];
                gsum[tid] = s;
            }
            __syncthreads();
            if (tid < 64) {
                int bl = tid >> 2, hp = (tid & 3) * 2;
                int b = bg * 16 + bl;
                const float* ei = embIH + (size_t)(t * 64 + b) * 2048 + cg * 32;
                union { f16 h[2]; unsigned u; } pk;
#pragma unroll
                for (int jj = 0; jj < 2; ++jj) {
                    int hh = hp + jj;
                    float gi = gsum[bl * 32 + hh] + ei[hh];
                    float gf = gsum[bl * 32 + 8 + hh] + ei[8 + hh];
                    float gg = gsum[bl * 32 + 16 + hh] + ei[16 + hh];
                    float go = gsum[bl * 32 + 24 + hh] + ei[24 + hh];
                    int ci = b * 512 + cg * 8 + hh;
                    float c = sigf(gf) * cbuf[ci] + sigf(gi) * tanhf(gg);
                    cbuf[ci] = c;
                    pk.h[jj] = (f16)(sigf(go) * tanhf(c));
                }
                ast_u((unsigned*)&hbuf[(size_t)(t + 1) * 32768 + b * 512 + cg * 8 + hp], pk.u);
            }
        }
        gbar(gsync, ++nbar);
    }
}

// ---------------------------------------------------------------------------
extern "C" void kernel_launch(void* const* d_in, const int* in_sizes, int n_in,
                              void* d_out, int out_size, void* d_ws, size_t ws_size,
                              hipStream_t stream)
{
    const float* enc  = (const float*)d_in[0];
    const int*   caps = (const int*)d_in[1];
    const int*   lens = (const int*)d_in[2];
    const float* emb  = (const float*)d_in[3];
    const float* W_ea = (const float*)d_in[4];
    const float* b_ea = (const float*)d_in[5];
    const float* W_da = (const float*)d_in[6];
    const float* b_da = (const float*)d_in[7];
    const float* W_fa = (const float*)d_in[8];
    const float* b_fa = (const float*)d_in[9];
    const float* W_fb = (const float*)d_in[10];
    const float* b_fb = (const float*)d_in[11];
    const float* W_ih = (const float*)d_in[12];
    const float* W_hh = (const float*)d_in[13];
    const float* b_ih = (const float*)d_in[14];
    const float* b_hh = (const float*)d_in[15];
    const float* W_fc = (const float*)d_in[16];
    const float* b_fc = (const float*)d_in[17];

    float* out = (float*)d_out;
    float* alph_out = out + (size_t)CB * CT * CV;

    char* p = (char*)d_ws;
    auto carve = [&](size_t bytes) {
        char* r = p;
        p += (bytes + 255) & ~(size_t)255;
        return r;
    };
    f16* enc_h   = (f16*)carve((size_t)12544 * 512 * 2);
    f16* att1_h  = (f16*)carve((size_t)12544 * 512 * 2);
    f16* Wea_h   = (f16*)carve((size_t)512 * 512 * 2);
    f16* Wdafb_h = (f16*)carve((size_t)1024 * 512 * 2);
    f16* WihE_p  = (f16*)carve((size_t)2048 * 512 * 2);
    f16* Bg_h    = (f16*)carve((size_t)2048 * 1024 * 2);
    f16* Wfc_h   = (f16*)carve((size_t)CVP * 512 * 2);
    f16* embg    = (f16*)carve((size_t)1280 * 512 * 2);
    float* embIH = (float*)carve((size_t)1280 * 2048 * 4);
    float* bcat  = (float*)carve(1024 * 4);
    float* bsum_p= (float*)carve(2048 * 4);
    f16* hbuf    = (f16*)carve((size_t)21 * 64 * 512 * 2);
    float* cbuf  = (float*)carve((size_t)64 * 512 * 4);
    f16* xh      = (f16*)carve((size_t)64 * 512 * 2);
    float* att2g = (float*)carve((size_t)64 * 1024 * 4);
    int* gsync   = (int*)carve(4096);

    hipLaunchKernelGGL(k_mega, dim3(4096), dim3(256), 0, stream,
                       enc, W_ea, W_da, W_fb, W_ih, W_hh, W_fc, emb, caps,
                       b_da, b_fb, b_ih, b_hh,
                       enc_h, Wea_h, Wdafb_h, WihE_p, Bg_h, Wfc_h, embg, bcat, bsum_p, gsync);

    hipLaunchKernelGGL(k_h0, dim3(64), dim3(256), 0, stream, enc, hbuf, cbuf);

    // att1 = enc_h @ W_ea^T + b_ea  (M=12544, N=512) -> f16
    hipLaunchKernelGGL((gemm_k512<EPI_F16B>), dim3(4, 98), dim3(256), 0, stream,
                       enc_h, Wea_h, 512, b_ea, (float*)nullptr, att1_h, (const int*)nullptr);
    // embIH = embg @ WihE_p^T + bsum_p  (M=1280, N=2048 permuted) -> f32
    hipLaunchKernelGGL((gemm_k512<EPI_F32B>), dim3(16, 10), dim3(256), 0, stream,
                       embg, WihE_p, 2048, bsum_p, embIH, (f16*)nullptr, (const int*)nullptr);

    // persistent 20-step loop: 256 blocks x 512 threads
    hipLaunchKernelGGL(k_loop, dim3(256), dim3(512), 0, stream,
                       att1_h, enc_h, Wdafb_h, Bg_h, embIH, W_fa, b_fa, bcat,
                       lens, hbuf, cbuf, xh, att2g, alph_out, gsync);

    // predictions = h(1..20) @ W_fc^T + b_fc, masked scatter
    hipLaunchKernelGGL((gemm_k512<EPI_PREDS>), dim3(10, CVP / 128), dim3(256), 0, stream,
                       hbuf + 32768, Wfc_h, CVP, b_fc, out, (f16*)nullptr, lens);
}